// Round 3
// baseline (658.868 us; speedup 1.0000x reference)
//
#include <hip/hip_runtime.h>
#include <hip/hip_bf16.h>

// Problem dims (fixed)
#define Bq 4
#define Sq 2048
#define Eq 768
#define Hq 3
#define Dq 256
#define BHq (Bq*Hq)

typedef __hip_bfloat16 bf16;
typedef __attribute__((ext_vector_type(8))) short bf16x8;
typedef __attribute__((ext_vector_type(4))) float f32x4;

__device__ __forceinline__ f32x4 mfma16(bf16x8 a, bf16x8 b, f32x4 c) {
    return __builtin_amdgcn_mfma_f32_16x16x32_bf16(a, b, c, 0, 0, 0);
}

__device__ __forceinline__ short f2bf(float x) {
    bf16 b = __float2bfloat16(x);
    return *(short*)&b;
}

// Pack 8 f32 (two float4s) -> bf16x8
__device__ __forceinline__ bf16x8 cvt8(float4 a, float4 b) {
    bf16x8 r;
    r[0] = f2bf(a.x); r[1] = f2bf(a.y); r[2] = f2bf(a.z); r[3] = f2bf(a.w);
    r[4] = f2bf(b.x); r[5] = f2bf(b.y); r[6] = f2bf(b.z); r[7] = f2bf(b.w);
    return r;
}

// ---------------------------------------------------------------------------
// Batched transpose + f32->bf16: in[batch][R][C] (f32) -> out[batch][C][R] (bf16)
// ---------------------------------------------------------------------------
__global__ __launch_bounds__(256) void transpose_f32_bf16(const float* __restrict__ in,
                                                          bf16* __restrict__ out,
                                                          int R, int C) {
    __shared__ float tile[32][33];
    const int bx = blockIdx.x * 32;   // col base (C dim)
    const int by = blockIdx.y * 32;   // row base (R dim)
    const int batch = blockIdx.z;
    in  += (size_t)batch * R * C;
    out += (size_t)batch * R * C;
    const int tx = threadIdx.x;       // 0..31
    const int ty = threadIdx.y;       // 0..7
#pragma unroll
    for (int i = ty; i < 32; i += 8)
        tile[i][tx] = in[(size_t)(by + i) * C + bx + tx];
    __syncthreads();
#pragma unroll
    for (int i = ty; i < 32; i += 8)
        out[(size_t)(bx + i) * R + by + tx] = __float2bfloat16(tile[tx][i]);
}

// ---------------------------------------------------------------------------
// Projection GEMMs: C[8192 x 256] = X[8192 x 768] (f32) @ W[h][768 x 256]
// sel: 0=K (store [b,h,s,d]), 1=V (store transposed [b,h,d,s]), 2=Q ([b,h,s,d])
// Wt inputs pre-transposed bf16: [h][d][e] (N-major, K-contiguous)
// Tile: BM=128 BN=128 BK=32; 4 waves, each 64x64 (4x4 frags of 16x16x32)
// ---------------------------------------------------------------------------
__global__ __launch_bounds__(256) void proj_kernel(
        const float* __restrict__ Xk, const float* __restrict__ Xv, const float* __restrict__ Xq,
        const bf16* __restrict__ WtK, const bf16* __restrict__ WtV, const bf16* __restrict__ WtQ,
        bf16* __restrict__ Kp, bf16* __restrict__ Vt, bf16* __restrict__ Qp) {
    const int sel = blockIdx.z;
    const int h   = blockIdx.y;
    const int mt  = blockIdx.x >> 1;
    const int nt  = blockIdx.x & 1;
    const float* X  = (sel == 0) ? Xk  : (sel == 1) ? Xv  : Xq;
    const bf16*  Wt = (sel == 0) ? WtK : (sel == 1) ? WtV : WtQ;

    // padded stride 40 (=80B, 16B aligned, breaks bank aliasing: 2-way max)
    __shared__ bf16 As[128 * 40];
    __shared__ bf16 Bs[128 * 40];

    const int tid  = threadIdx.x;
    const int lane = tid & 63;
    const int w    = tid >> 6;
    const int quad = lane >> 4;
    const int l16  = lane & 15;
    const int wm   = (w & 1) * 64;
    const int wn   = (w >> 1) * 64;

    const int m0 = mt * 128;   // global token-row base [0,8192)
    const int n0 = nt * 128;   // d base

    f32x4 acc[4][4] = {};

    for (int k0 = 0; k0 < Eq; k0 += 32) {
        // stage A (128x32, f32->bf16) and B (128x32 bf16): 512 chunks each, 2/thread
#pragma unroll
        for (int i = 0; i < 2; ++i) {
            int c = tid * 2 + i;
            int r = c >> 2, cc = c & 3;
            const float* xp = &X[(size_t)(m0 + r) * Eq + k0 + cc * 8];
            float4 v0 = ((const float4*)xp)[0];
            float4 v1 = ((const float4*)xp)[1];
            *(bf16x8*)&As[r * 40 + cc * 8] = cvt8(v0, v1);
            *(bf16x8*)&Bs[r * 40 + cc * 8] =
                *(const bf16x8*)&Wt[(size_t)(h * Dq + n0 + r) * Eq + k0 + cc * 8];
        }
        __syncthreads();
        bf16x8 af[4], bfr[4];
#pragma unroll
        for (int mi = 0; mi < 4; ++mi)
            af[mi] = *(const bf16x8*)&As[(wm + mi * 16 + l16) * 40 + quad * 8];
#pragma unroll
        for (int ni = 0; ni < 4; ++ni)
            bfr[ni] = *(const bf16x8*)&Bs[(wn + ni * 16 + l16) * 40 + quad * 8];
#pragma unroll
        for (int mi = 0; mi < 4; ++mi)
#pragma unroll
            for (int ni = 0; ni < 4; ++ni)
                acc[mi][ni] = mfma16(af[mi], bfr[ni], acc[mi][ni]);
        __syncthreads();
    }

    // store: C/D layout row=quad*4+r col=l16
    const int b  = m0 / Sq;
    const int s0 = m0 % Sq;
    const int bh = b * Hq + h;
#pragma unroll
    for (int mi = 0; mi < 4; ++mi) {
#pragma unroll
        for (int ni = 0; ni < 4; ++ni) {
#pragma unroll
            for (int r = 0; r < 4; ++r) {
                int s = s0 + wm + mi * 16 + quad * 4 + r;
                int d = n0 + wn + ni * 16 + l16;
                bf16 v = __float2bfloat16(acc[mi][ni][r]);
                if (sel == 1)
                    Vt[(size_t)(bh * Dq + d) * Sq + s] = v;
                else if (sel == 0)
                    Kp[(size_t)(bh * Sq + s) * Dq + d] = v;
                else
                    Qp[(size_t)(bh * Sq + s) * Dq + d] = v;
            }
        }
    }
}

// ---------------------------------------------------------------------------
// Flash attention: per (qb, bh) workgroup. 4 waves x 16 q-rows = 64 q-rows.
// K-tiles of 64 keys. scale = 1/sqrt(2048). Causal.
// K tile and V tile share one 32KB LDS buffer (staged sequentially).
// XOR-swizzled 16B chunks (phys = cc ^ (row&7)) for conflict-free ds_read_b128.
// ---------------------------------------------------------------------------
__global__ __launch_bounds__(256) void attn_kernel(
        const bf16* __restrict__ Qp, const bf16* __restrict__ Kp,
        const bf16* __restrict__ Vt, bf16* __restrict__ Z) {
    __shared__ bf16 KV[64 * 256];     // 32KB: K tile [64key][256d] then V tile [256d][64key]
    __shared__ bf16 Pl[4 * 16 * 64];  // 8KB per-wave P (A-layout round trip)

    const float SCALE = 0.022097086912079608f;  // 1/sqrt(2048)

    const int qb = blockIdx.x;   // 0..31
    const int bh = blockIdx.y;   // 0..11
    const int tid  = threadIdx.x;
    const int lane = tid & 63;
    const int w    = tid >> 6;
    const int quad = lane >> 4;
    const int l16  = lane & 15;

    const int q0 = qb * 64 + w * 16;  // wave's q-row base

    // Q fragments: A[m=l16][k=c*32+quad*8+j], 8 chunks over D=256
    bf16x8 qf[8];
    {
        const bf16* Qbase = Qp + (size_t)(bh * Sq + q0 + l16) * Dq;
#pragma unroll
        for (int c = 0; c < 8; ++c)
            qf[c] = *(const bf16x8*)&Qbase[c * 32 + quad * 8];
    }

    f32x4 o[16] = {};
    float m_i[4], l_i[4];
#pragma unroll
    for (int r = 0; r < 4; ++r) { m_i[r] = -INFINITY; l_i[r] = 0.0f; }

    const int ntiles = qb + 1;  // causal: keys <= q0+63
    for (int kt = 0; kt < ntiles; ++kt) {
        const int k0 = kt * 64;

        // ---- stage K tile: 64 rows x 256 d (2048 chunks of 16B, 8/thread) ----
#pragma unroll
        for (int p = 0; p < 8; ++p) {
            int c = p * 256 + tid;
            int row = c >> 5, cc = c & 31;
            int pcc = cc ^ (row & 7);
            *(bf16x8*)&KV[row * 256 + pcc * 8] =
                *(const bf16x8*)&Kp[(size_t)(bh * Sq + k0 + row) * Dq + cc * 8];
        }
        __syncthreads();

        // ---- scores: S[16q x 64key] per wave ----
        f32x4 sf[4] = {};
#pragma unroll
        for (int c = 0; c < 8; ++c) {
#pragma unroll
            for (int ni = 0; ni < 4; ++ni) {
                int key = ni * 16 + l16;
                int cc  = c * 4 + quad;
                bf16x8 kf = *(const bf16x8*)&KV[key * 256 + (cc ^ (key & 7)) * 8];
                sf[ni] = mfma16(qf[c], kf, sf[ni]);
            }
        }

        // ---- online softmax (rows quad*4+r owned by this quad's 16 lanes) ----
        float pv[4][4];
        float rmax[4];
#pragma unroll
        for (int r = 0; r < 4; ++r) rmax[r] = -INFINITY;
        const bool diag = (kt == qb);
#pragma unroll
        for (int ni = 0; ni < 4; ++ni) {
#pragma unroll
            for (int r = 0; r < 4; ++r) {
                float v = sf[ni][r] * SCALE;
                if (diag) {
                    int kg = k0 + ni * 16 + l16;
                    int qg = qb * 64 + w * 16 + quad * 4 + r;
                    if (kg > qg) v = -INFINITY;
                }
                pv[ni][r] = v;
                rmax[r] = fmaxf(rmax[r], v);
            }
        }
#pragma unroll
        for (int off = 1; off < 16; off <<= 1)
#pragma unroll
            for (int r = 0; r < 4; ++r)
                rmax[r] = fmaxf(rmax[r], __shfl_xor(rmax[r], off));

        float alpha[4], rsum[4];
#pragma unroll
        for (int r = 0; r < 4; ++r) {
            float mnew = fmaxf(m_i[r], rmax[r]);
            alpha[r] = __expf(m_i[r] - mnew);
            m_i[r] = mnew;
            float s = 0.0f;
#pragma unroll
            for (int ni = 0; ni < 4; ++ni) {
                float e = __expf(pv[ni][r] - mnew);
                pv[ni][r] = e;
                s += e;
            }
            rsum[r] = s;
        }
#pragma unroll
        for (int off = 1; off < 16; off <<= 1)
#pragma unroll
            for (int r = 0; r < 4; ++r)
                rsum[r] += __shfl_xor(rsum[r], off);
#pragma unroll
        for (int r = 0; r < 4; ++r) l_i[r] = l_i[r] * alpha[r] + rsum[r];
        // rescale O
#pragma unroll
        for (int ni = 0; ni < 16; ++ni)
#pragma unroll
            for (int r = 0; r < 4; ++r) o[ni][r] *= alpha[r];

        __syncthreads();  // all waves done reading K tile

        // ---- stage V tile into same buffer: rows d 0..255 x 64 keys ----
#pragma unroll
        for (int p = 0; p < 8; ++p) {
            int c = p * 256 + tid;
            int row = c >> 3, cc = c & 7;
            int pcc = cc ^ (row & 7);
            *(bf16x8*)&KV[row * 64 + pcc * 8] =
                *(const bf16x8*)&Vt[(size_t)(bh * Dq + row) * Sq + k0 + cc * 8];
        }
        // ---- write P to per-wave LDS (C-layout -> A-layout round trip) ----
#pragma unroll
        for (int ni = 0; ni < 4; ++ni) {
#pragma unroll
            for (int r = 0; r < 4; ++r) {
                int row = quad * 4 + r;
                int col = ni * 16 + l16;
                int cc  = col >> 3;
                int pcc = cc ^ (row & 7);
                Pl[w * 1024 + row * 64 + pcc * 8 + (col & 7)] = __float2bfloat16(pv[ni][r]);
            }
        }
        __syncthreads();  // V staged (and P visible)

        // ---- PV: O[16q x 256d] += P[16q x 64k] @ V[64k x 256d] ----
#pragma unroll
        for (int c2 = 0; c2 < 2; ++c2) {
            int cc = c2 * 4 + quad;  // logical 16B chunk within 64-key row
            bf16x8 af = *(const bf16x8*)&Pl[w * 1024 + l16 * 64 + (cc ^ (l16 & 7)) * 8];
#pragma unroll
            for (int ni = 0; ni < 16; ++ni) {
                int d = ni * 16 + l16;
                bf16x8 vf = *(const bf16x8*)&KV[d * 64 + (cc ^ (d & 7)) * 8];
                o[ni] = mfma16(af, vf, o[ni]);
            }
        }
        __syncthreads();  // done reading V before next K staging
    }

    // ---- epilogue: Z[b][s][h*256 + d] = O / l ----
    const int b = bh / Hq, h = bh % Hq;
#pragma unroll
    for (int ni = 0; ni < 16; ++ni) {
#pragma unroll
        for (int r = 0; r < 4; ++r) {
            int s = q0 + quad * 4 + r;
            int e = h * Dq + ni * 16 + l16;
            Z[(size_t)(b * Sq + s) * Eq + e] = __float2bfloat16(o[ni][r] / l_i[r]);
        }
    }
}

// ---------------------------------------------------------------------------
// Output projection: out[8192 x 768] (f32!) = Z[8192 x 768] @ Wo[768 x 768] + bo
// Wot pre-transposed bf16 [out_e][in_e]. bo is f32. Same tile structure as proj.
// ---------------------------------------------------------------------------
__global__ __launch_bounds__(256) void outproj_kernel(
        const bf16* __restrict__ Z, const bf16* __restrict__ Wot,
        const float* __restrict__ bo, float* __restrict__ out) {
    const int mt = blockIdx.x;
    const int nt = blockIdx.y;

    __shared__ bf16 As[128 * 40];
    __shared__ bf16 Bs[128 * 40];

    const int tid  = threadIdx.x;
    const int lane = tid & 63;
    const int w    = tid >> 6;
    const int quad = lane >> 4;
    const int l16  = lane & 15;
    const int wm   = (w & 1) * 64;
    const int wn   = (w >> 1) * 64;

    const int m0 = mt * 128;
    const int n0 = nt * 128;

    f32x4 acc[4][4] = {};

    for (int k0 = 0; k0 < Eq; k0 += 32) {
#pragma unroll
        for (int i = 0; i < 2; ++i) {
            int c = tid * 2 + i;
            int r = c >> 2, cc = c & 3;
            *(bf16x8*)&As[r * 40 + cc * 8] =
                *(const bf16x8*)&Z[(size_t)(m0 + r) * Eq + k0 + cc * 8];
            *(bf16x8*)&Bs[r * 40 + cc * 8] =
                *(const bf16x8*)&Wot[(size_t)(n0 + r) * Eq + k0 + cc * 8];
        }
        __syncthreads();
        bf16x8 af[4], bfr[4];
#pragma unroll
        for (int mi = 0; mi < 4; ++mi)
            af[mi] = *(const bf16x8*)&As[(wm + mi * 16 + l16) * 40 + quad * 8];
#pragma unroll
        for (int ni = 0; ni < 4; ++ni)
            bfr[ni] = *(const bf16x8*)&Bs[(wn + ni * 16 + l16) * 40 + quad * 8];
#pragma unroll
        for (int mi = 0; mi < 4; ++mi)
#pragma unroll
            for (int ni = 0; ni < 4; ++ni)
                acc[mi][ni] = mfma16(af[mi], bfr[ni], acc[mi][ni]);
        __syncthreads();
    }

#pragma unroll
    for (int ni = 0; ni < 4; ++ni) {
        int n = n0 + wn + ni * 16 + l16;
        float bias = bo[n];
#pragma unroll
        for (int mi = 0; mi < 4; ++mi) {
#pragma unroll
            for (int r = 0; r < 4; ++r) {
                int m = m0 + wm + mi * 16 + quad * 4 + r;
                out[(size_t)m * Eq + n] = acc[mi][ni][r] + bias;
            }
        }
    }
}

// ---------------------------------------------------------------------------
extern "C" void kernel_launch(void* const* d_in, const int* in_sizes, int n_in,
                              void* d_out, int out_size, void* d_ws, size_t ws_size,
                              hipStream_t stream) {
    const float* Xk = (const float*)d_in[0];
    const float* Xv = (const float*)d_in[1];
    const float* Xq = (const float*)d_in[2];
    const float* WK = (const float*)d_in[3];
    const float* WV = (const float*)d_in[4];
    const float* WQ = (const float*)d_in[5];
    const float* Wo = (const float*)d_in[6];
    const float* bo = (const float*)d_in[7];
    float* out = (float*)d_out;   // reference output dtype is float32

    // workspace layout (bf16 elements)
    bf16* ws = (bf16*)d_ws;
    const size_t WSZ  = (size_t)Hq * Eq * Dq;   // 589824 per stacked weight
    const size_t QKV  = (size_t)BHq * Sq * Dq;  // 6291456
    bf16* WtK = ws;                 // [h][d][e]
    bf16* WtV = WtK + WSZ;
    bf16* WtQ = WtV + WSZ;
    bf16* WtO = WtQ + WSZ;          // [out_e][in_e]
    bf16* Qp  = WtO + (size_t)Eq * Eq;
    bf16* Kp  = Qp + QKV;           // [b,h,s,d]
    bf16* Vt  = Kp + QKV;           // [b,h,d,s]
    bf16* Zb  = Vt + QKV;           // [b,s,e]

    dim3 tblk(32, 8);
    transpose_f32_bf16<<<dim3(Dq / 32, Eq / 32, Hq), tblk, 0, stream>>>(WK, WtK, Eq, Dq);
    transpose_f32_bf16<<<dim3(Dq / 32, Eq / 32, Hq), tblk, 0, stream>>>(WV, WtV, Eq, Dq);
    transpose_f32_bf16<<<dim3(Dq / 32, Eq / 32, Hq), tblk, 0, stream>>>(WQ, WtQ, Eq, Dq);
    transpose_f32_bf16<<<dim3(Eq / 32, Eq / 32, 1), tblk, 0, stream>>>(Wo, WtO, Eq, Eq);

    proj_kernel<<<dim3(128, Hq, 3), 256, 0, stream>>>(Xk, Xv, Xq, WtK, WtV, WtQ, Kp, Vt, Qp);
    attn_kernel<<<dim3(Sq / 64, BHq), 256, 0, stream>>>(Qp, Kp, Vt, Zb);
    outproj_kernel<<<dim3(64, 6), 256, 0, stream>>>(Zb, WtO, bo, out);
}